// Round 1
// baseline (526.729 us; speedup 1.0000x reference)
//
#include <hip/hip_runtime.h>
#include <math.h>

// Match numpy (no FMA contraction) — mask boundary is bit-sensitive.
#pragma clang fp contract(off)

namespace {

constexpr int B = 12, H = 192, W = 640;
constexpr int HW  = H * W;        // 122880
constexpr int BHW = B * HW;       // 1474560
constexpr float EPS = 1e-7f;
constexpr int TPB = 256;

__device__ __forceinline__ void atomicMinF(float* a, float v) {
    if (v >= 0.0f) atomicMin((int*)a, __float_as_int(v));
    else           atomicMax((unsigned int*)a, __float_as_uint(v));
}
__device__ __forceinline__ void atomicMaxF(float* a, float v) {
    if (v >= 0.0f) atomicMax((int*)a, __float_as_int(v));
    else           atomicMin((unsigned int*)a, __float_as_uint(v));
}

// static flow = project(K@pose, depth*unproject(invK,[x,y,1])) - [x,y]
// Accumulation order mirrors the reference einsums (left-assoc, f32).
__device__ __forceinline__ void static_flow(
    const float* __restrict__ Km, const float* __restrict__ invK,
    const float* __restrict__ pose, int b, int x, int y, float d,
    float& sx, float& sy)
{
    const float* Kb = Km   + b * 16;
    const float* iK = invK + b * 16;
    const float* Po = pose + b * 16;
    float fx = (float)x, fy = (float)y;
    // cam = invK[:3,:3] @ [x,y,1]
    float cam0 = iK[0]*fx + iK[1]*fy + iK[2];
    float cam1 = iK[4]*fx + iK[5]*fy + iK[6];
    float cam2 = iK[8]*fx + iK[9]*fy + iK[10];
    cam0 = d * cam0; cam1 = d * cam1; cam2 = d * cam2;
    // P = (K @ pose)[:3,:]
    float P[12];
#pragma unroll
    for (int i = 0; i < 3; ++i) {
#pragma unroll
        for (int j = 0; j < 4; ++j) {
            float s = Kb[i*4+0] * Po[0*4+j];
            s = s + Kb[i*4+1] * Po[1*4+j];
            s = s + Kb[i*4+2] * Po[2*4+j];
            s = s + Kb[i*4+3] * Po[3*4+j];
            P[i*4+j] = s;
        }
    }
    // cp = P @ [cam0,cam1,cam2,1]
    float cp0 = P[0]*cam0 + P[1]*cam1 + P[2]*cam2  + P[3];
    float cp1 = P[4]*cam0 + P[5]*cam1 + P[6]*cam2  + P[7];
    float cp2 = P[8]*cam0 + P[9]*cam1 + P[10]*cam2 + P[11];
    float pz = cp2 + EPS;
    sx = cp0 / pz - fx;
    sy = cp1 / pz - fy;
}

__device__ __forceinline__ float norm01(float v, float mn, float mx) {
    return (2.0f * (v - mn)) / (mx - mn) - 1.0f;
}

// ws layout: scal[0..5] = {fmin,fmax,smin,smax,cmin,cmax}; winner[BHW] ints at +64B

__global__ void k_init(float* __restrict__ out, int* __restrict__ winner,
                       float* __restrict__ scal) {
    int i = blockIdx.x * blockDim.x + threadIdx.x;
    if (i < 3 * BHW) out[BHW + i] = 0.0f;     // bwd_flow + seg_ref regions
    if (i < BHW)     winner[i] = -1;
    if (i == 0) {
        scal[0] = INFINITY;  scal[1] = -INFINITY;
        scal[2] = INFINITY;  scal[3] = -INFINITY;
        scal[4] = INFINITY;  scal[5] = -INFINITY;
    }
}

// Pass 1: flow & static min/max + winner scatter (atomicMax, last-index-wins)
__global__ void k_pass1(const float* __restrict__ flow, const float* __restrict__ depth,
                        const float* __restrict__ Km, const float* __restrict__ invK,
                        const float* __restrict__ pose,
                        float* __restrict__ scal, int* __restrict__ winner) {
    int p = blockIdx.x * blockDim.x + threadIdx.x;
    float fmn = INFINITY, fmx = -INFINITY, smn = INFINITY, smx = -INFINITY;
    if (p < BHW) {
        int b = p / HW;
        int n = p - b * HW;
        int y = n / W;
        int x = n - y * W;
        float fxv = flow[b*2*HW + n];
        float fyv = flow[b*2*HW + HW + n];
        float d   = depth[p];
        float sx, sy;
        static_flow(Km, invK, pose, b, x, y, d, sx, sy);
        fmn = fminf(fxv, fyv); fmx = fmaxf(fxv, fyv);
        smn = fminf(sx, sy);   smx = fmaxf(sx, sy);
        // invert_flow target: round (half-to-even, matches jnp.round), clip
        int cxi = (int)rintf((float)x + fxv);
        int cyi = (int)rintf((float)y + fyv);
        cxi = min(max(cxi, 0), W - 1);
        cyi = min(max(cyi, 0), H - 1);
        atomicMax(&winner[b*HW + cyi*W + cxi], n);
    }
    // wave reduce (64 lanes)
    for (int off = 32; off; off >>= 1) {
        fmn = fminf(fmn, __shfl_down(fmn, off, 64));
        fmx = fmaxf(fmx, __shfl_down(fmx, off, 64));
        smn = fminf(smn, __shfl_down(smn, off, 64));
        smx = fmaxf(smx, __shfl_down(smx, off, 64));
    }
    __shared__ float s[4][4];
    int lane = threadIdx.x & 63, wv = threadIdx.x >> 6;
    if (lane == 0) { s[wv][0]=fmn; s[wv][1]=fmx; s[wv][2]=smn; s[wv][3]=smx; }
    __syncthreads();
    if (threadIdx.x == 0) {
        float a = s[0][0], bq = s[0][1], c = s[0][2], dq = s[0][3];
#pragma unroll
        for (int w2 = 1; w2 < 4; ++w2) {
            a  = fminf(a,  s[w2][0]); bq = fmaxf(bq, s[w2][1]);
            c  = fminf(c,  s[w2][2]); dq = fmaxf(dq, s[w2][3]);
        }
        atomicMinF(&scal[0], a);  atomicMaxF(&scal[1], bq);
        atomicMinF(&scal[2], c);  atomicMaxF(&scal[3], dq);
    }
}

// Pass 2: check min/max
__global__ void k_pass2(const float* __restrict__ flow, const float* __restrict__ depth,
                        const float* __restrict__ Km, const float* __restrict__ invK,
                        const float* __restrict__ pose, float* __restrict__ scal) {
    int p = blockIdx.x * blockDim.x + threadIdx.x;
    float fmn = scal[0], fmx = scal[1], smn = scal[2], smx = scal[3];
    float cmn = INFINITY, cmx = -INFINITY;
    if (p < BHW) {
        int b = p / HW;
        int n = p - b * HW;
        int y = n / W;
        int x = n - y * W;
        float fxv = flow[b*2*HW + n];
        float fyv = flow[b*2*HW + HW + n];
        float d   = depth[p];
        float sx, sy;
        static_flow(Km, invK, pose, b, x, y, d, sx, sy);
        float dx = norm01(fxv, fmn, fmx) - norm01(sx, smn, smx);
        float dy = norm01(fyv, fmn, fmx) - norm01(sy, smn, smx);
        float c = sqrtf(dx*dx + dy*dy);
        cmn = c; cmx = c;
    }
    for (int off = 32; off; off >>= 1) {
        cmn = fminf(cmn, __shfl_down(cmn, off, 64));
        cmx = fmaxf(cmx, __shfl_down(cmx, off, 64));
    }
    __shared__ float s[4][2];
    int lane = threadIdx.x & 63, wv = threadIdx.x >> 6;
    if (lane == 0) { s[wv][0] = cmn; s[wv][1] = cmx; }
    __syncthreads();
    if (threadIdx.x == 0) {
        float a = s[0][0], bq = s[0][1];
#pragma unroll
        for (int w2 = 1; w2 < 4; ++w2) { a = fminf(a, s[w2][0]); bq = fmaxf(bq, s[w2][1]); }
        atomicMinF(&scal[4], a);  atomicMaxF(&scal[5], bq);
    }
}

// Pass 3: mask write + winner-resolved scatter of (-flow, seg)
__global__ void k_pass3(const float* __restrict__ flow, const float* __restrict__ depth,
                        const int* __restrict__ seg,
                        const float* __restrict__ Km, const float* __restrict__ invK,
                        const float* __restrict__ pose,
                        const float* __restrict__ scal, const int* __restrict__ winner,
                        float* __restrict__ out) {
    int p = blockIdx.x * blockDim.x + threadIdx.x;
    if (p >= BHW) return;
    float fmn = scal[0], fmx = scal[1], smn = scal[2], smx = scal[3];
    float cmn = scal[4], cmx = scal[5];
    int b = p / HW;
    int n = p - b * HW;
    int y = n / W;
    int x = n - y * W;
    float fxv = flow[b*2*HW + n];
    float fyv = flow[b*2*HW + HW + n];
    float d   = depth[p];
    float sx, sy;
    static_flow(Km, invK, pose, b, x, y, d, sx, sy);
    float dx = norm01(fxv, fmn, fmx) - norm01(sx, smn, smx);
    float dy = norm01(fyv, fmn, fmx) - norm01(sy, smn, smx);
    float c = sqrtf(dx*dx + dy*dy);
    float cn = (c - cmn) / (cmx - cmn);
    out[p] = (cn < 0.98f) ? 1.0f : 0.0f;

    int cxi = (int)rintf((float)x + fxv);
    int cyi = (int)rintf((float)y + fyv);
    cxi = min(max(cxi, 0), W - 1);
    cyi = min(max(cyi, 0), H - 1);
    int idx = cyi * W + cxi;
    if (winner[b*HW + idx] == n) {
        out[BHW + b*2*HW + idx]      = -fxv;
        out[BHW + b*2*HW + HW + idx] = -fyv;
        out[3*BHW + b*HW + idx]      = seg[p] ? 1.0f : 0.0f;
    }
}

} // namespace

extern "C" void kernel_launch(void* const* d_in, const int* in_sizes, int n_in,
                              void* d_out, int out_size, void* d_ws, size_t ws_size,
                              hipStream_t stream) {
    const float* flow  = (const float*)d_in[0];
    const float* depth = (const float*)d_in[1];
    const float* Km    = (const float*)d_in[2];
    const float* invK  = (const float*)d_in[3];
    const float* pose  = (const float*)d_in[4];
    const int*   seg   = (const int*)d_in[5];
    float* out  = (float*)d_out;
    float* scal = (float*)d_ws;
    int*   winner = (int*)((char*)d_ws + 64);

    int gInit = (3 * BHW + TPB - 1) / TPB;
    int gMain = (BHW + TPB - 1) / TPB;   // 5760 blocks
    k_init <<<gInit, TPB, 0, stream>>>(out, winner, scal);
    k_pass1<<<gMain, TPB, 0, stream>>>(flow, depth, Km, invK, pose, scal, winner);
    k_pass2<<<gMain, TPB, 0, stream>>>(flow, depth, Km, invK, pose, scal);
    k_pass3<<<gMain, TPB, 0, stream>>>(flow, depth, seg, Km, invK, pose, scal, winner, out);
}

// Round 2
// 507.692 us; speedup vs baseline: 1.0375x; 1.0375x over previous
//
#include <hip/hip_runtime.h>
#include <hip/hip_fp16.h>
#include <math.h>

// Match numpy (no FMA contraction) — mask boundary is bit-sensitive.
#pragma clang fp contract(off)

namespace {

constexpr int B = 12, H = 192, W = 640;
constexpr int HW  = H * W;        // 122880
constexpr int BHW = B * HW;       // 1474560
constexpr float EPS = 1e-7f;
constexpr int TPB = 256;

// ws layout:
//   [0..15]   float mins[4]   : {fmin, smin, cmin, pad}   memset 0x7F -> +3.39e38
//   [16..31]  float maxs[4]   : {fmax, smax, cmax, pad}   memset 0xFF -> -NaN (works w/ int-atomics)
//   [256 ...] uint64 A[BHW]   : packed winner records, memset 0

__device__ __forceinline__ void atomicMinF(float* a, float v) {
    if (v >= 0.0f) atomicMin((int*)a, __float_as_int(v));
    else           atomicMax((unsigned int*)a, __float_as_uint(v));
}
__device__ __forceinline__ void atomicMaxF(float* a, float v) {
    if (v >= 0.0f) atomicMax((int*)a, __float_as_int(v));
    else           atomicMin((unsigned int*)a, __float_as_uint(v));
}

// static flow = project(K@pose, depth*unproject(invK,[x,y,1])) - [x,y]
// Accumulation order mirrors the reference einsums (left-assoc, f32).
__device__ __forceinline__ void static_flow(
    const float* __restrict__ Km, const float* __restrict__ invK,
    const float* __restrict__ pose, int b, int x, int y, float d,
    float& sx, float& sy)
{
    const float* Kb = Km   + b * 16;
    const float* iK = invK + b * 16;
    const float* Po = pose + b * 16;
    float fx = (float)x, fy = (float)y;
    float cam0 = iK[0]*fx + iK[1]*fy + iK[2];
    float cam1 = iK[4]*fx + iK[5]*fy + iK[6];
    float cam2 = iK[8]*fx + iK[9]*fy + iK[10];
    cam0 = d * cam0; cam1 = d * cam1; cam2 = d * cam2;
    float P[12];
#pragma unroll
    for (int i = 0; i < 3; ++i) {
#pragma unroll
        for (int j = 0; j < 4; ++j) {
            float s = Kb[i*4+0] * Po[0*4+j];
            s = s + Kb[i*4+1] * Po[1*4+j];
            s = s + Kb[i*4+2] * Po[2*4+j];
            s = s + Kb[i*4+3] * Po[3*4+j];
            P[i*4+j] = s;
        }
    }
    float cp0 = P[0]*cam0 + P[1]*cam1 + P[2]*cam2  + P[3];
    float cp1 = P[4]*cam0 + P[5]*cam1 + P[6]*cam2  + P[7];
    float cp2 = P[8]*cam0 + P[9]*cam1 + P[10]*cam2 + P[11];
    float pz = cp2 + EPS;
    sx = cp0 / pz - fx;
    sy = cp1 / pz - fy;
}

__device__ __forceinline__ float norm01(float v, float mn, float mx) {
    return (2.0f * (v - mn)) / (mx - mn) - 1.0f;
}

// Pass 1: flow & static min/max + ONE packed 64-bit atomicMax per source.
// key = (n+1)<<33 | seg<<32 | h(-fx)<<16 | h(-fy); max key == max n (unique),
// so last-write-wins AND the winner's payload rides along.
__global__ void k_pass1(const float* __restrict__ flow, const float* __restrict__ depth,
                        const int* __restrict__ seg,
                        const float* __restrict__ Km, const float* __restrict__ invK,
                        const float* __restrict__ pose,
                        float* __restrict__ mins, float* __restrict__ maxs,
                        unsigned long long* __restrict__ A) {
    int p = blockIdx.x * blockDim.x + threadIdx.x;
    float fmn = INFINITY, fmx = -INFINITY, smn = INFINITY, smx = -INFINITY;
    if (p < BHW) {
        int b = p / HW;
        int n = p - b * HW;
        int y = n / W;
        int x = n - y * W;
        float fxv = flow[b*2*HW + n];
        float fyv = flow[b*2*HW + HW + n];
        float d   = depth[p];
        float sx, sy;
        static_flow(Km, invK, pose, b, x, y, d, sx, sy);
        fmn = fminf(fxv, fyv); fmx = fmaxf(fxv, fyv);
        smn = fminf(sx, sy);   smx = fmaxf(sx, sy);
        // invert_flow target: round (half-to-even, matches jnp.round), clip
        int cxi = (int)rintf((float)x + fxv);
        int cyi = (int)rintf((float)y + fyv);
        cxi = min(max(cxi, 0), W - 1);
        cyi = min(max(cyi, 0), H - 1);
        unsigned long long hx = (unsigned long long)__half_as_ushort(__float2half(-fxv));
        unsigned long long hy = (unsigned long long)__half_as_ushort(__float2half(-fyv));
        unsigned long long sg = seg[p] ? 1ull : 0ull;
        unsigned long long key = ((unsigned long long)(n + 1) << 33) | (sg << 32)
                               | (hx << 16) | hy;
        atomicMax(&A[b*HW + cyi*W + cxi], key);
    }
    for (int off = 32; off; off >>= 1) {
        fmn = fminf(fmn, __shfl_down(fmn, off, 64));
        fmx = fmaxf(fmx, __shfl_down(fmx, off, 64));
        smn = fminf(smn, __shfl_down(smn, off, 64));
        smx = fmaxf(smx, __shfl_down(smx, off, 64));
    }
    __shared__ float s[4][4];
    int lane = threadIdx.x & 63, wv = threadIdx.x >> 6;
    if (lane == 0) { s[wv][0]=fmn; s[wv][1]=fmx; s[wv][2]=smn; s[wv][3]=smx; }
    __syncthreads();
    if (threadIdx.x == 0) {
        float a = s[0][0], bq = s[0][1], c = s[0][2], dq = s[0][3];
#pragma unroll
        for (int w2 = 1; w2 < 4; ++w2) {
            a  = fminf(a,  s[w2][0]); bq = fmaxf(bq, s[w2][1]);
            c  = fminf(c,  s[w2][2]); dq = fmaxf(dq, s[w2][3]);
        }
        atomicMinF(&mins[0], a);  atomicMaxF(&maxs[0], bq);
        atomicMinF(&mins[1], c);  atomicMaxF(&maxs[1], dq);
    }
}

// Pass 2: check min/max
__global__ void k_pass2(const float* __restrict__ flow, const float* __restrict__ depth,
                        const float* __restrict__ Km, const float* __restrict__ invK,
                        const float* __restrict__ pose,
                        float* __restrict__ mins, float* __restrict__ maxs) {
    int p = blockIdx.x * blockDim.x + threadIdx.x;
    float fmn = mins[0], fmx = maxs[0], smn = mins[1], smx = maxs[1];
    float cmn = INFINITY, cmx = -INFINITY;
    if (p < BHW) {
        int b = p / HW;
        int n = p - b * HW;
        int y = n / W;
        int x = n - y * W;
        float fxv = flow[b*2*HW + n];
        float fyv = flow[b*2*HW + HW + n];
        float d   = depth[p];
        float sx, sy;
        static_flow(Km, invK, pose, b, x, y, d, sx, sy);
        float dx = norm01(fxv, fmn, fmx) - norm01(sx, smn, smx);
        float dy = norm01(fyv, fmn, fmx) - norm01(sy, smn, smx);
        float c = sqrtf(dx*dx + dy*dy);
        cmn = c; cmx = c;
    }
    for (int off = 32; off; off >>= 1) {
        cmn = fminf(cmn, __shfl_down(cmn, off, 64));
        cmx = fmaxf(cmx, __shfl_down(cmx, off, 64));
    }
    __shared__ float s[4][2];
    int lane = threadIdx.x & 63, wv = threadIdx.x >> 6;
    if (lane == 0) { s[wv][0] = cmn; s[wv][1] = cmx; }
    __syncthreads();
    if (threadIdx.x == 0) {
        float a = s[0][0], bq = s[0][1];
#pragma unroll
        for (int w2 = 1; w2 < 4; ++w2) { a = fminf(a, s[w2][0]); bq = fmaxf(bq, s[w2][1]); }
        atomicMinF(&mins[2], a);  atomicMaxF(&maxs[2], bq);
    }
}

// Pass 3: mask write + fully-coalesced extraction of packed winners.
__global__ void k_pass3(const float* __restrict__ flow, const float* __restrict__ depth,
                        const float* __restrict__ Km, const float* __restrict__ invK,
                        const float* __restrict__ pose,
                        const float* __restrict__ mins, const float* __restrict__ maxs,
                        const unsigned long long* __restrict__ A,
                        float* __restrict__ out) {
    int p = blockIdx.x * blockDim.x + threadIdx.x;
    if (p >= BHW) return;
    float fmn = mins[0], fmx = maxs[0], smn = mins[1], smx = maxs[1];
    float cmn = mins[2], cmx = maxs[2];
    int b = p / HW;
    int n = p - b * HW;
    int y = n / W;
    int x = n - y * W;
    float fxv = flow[b*2*HW + n];
    float fyv = flow[b*2*HW + HW + n];
    float d   = depth[p];
    float sx, sy;
    static_flow(Km, invK, pose, b, x, y, d, sx, sy);
    float dx = norm01(fxv, fmn, fmx) - norm01(sx, smn, smx);
    float dy = norm01(fyv, fmn, fmx) - norm01(sy, smn, smx);
    float c = sqrtf(dx*dx + dy*dy);
    float cn = (c - cmn) / (cmx - cmn);
    out[p] = (cn < 0.98f) ? 1.0f : 0.0f;

    // extraction: target index == p (coalesced read A, coalesced writes)
    unsigned long long k = A[p];
    float bx = 0.0f, by = 0.0f, sg = 0.0f;
    if (k != 0ull) {
        sg = (float)((k >> 32) & 1ull);
        bx = __half2float(__ushort_as_half((unsigned short)((k >> 16) & 0xFFFFull)));
        by = __half2float(__ushort_as_half((unsigned short)(k & 0xFFFFull)));
    }
    out[BHW + b*2*HW + n]      = bx;
    out[BHW + b*2*HW + HW + n] = by;
    out[3*BHW + p]             = sg;
}

} // namespace

extern "C" void kernel_launch(void* const* d_in, const int* in_sizes, int n_in,
                              void* d_out, int out_size, void* d_ws, size_t ws_size,
                              hipStream_t stream) {
    const float* flow  = (const float*)d_in[0];
    const float* depth = (const float*)d_in[1];
    const float* Km    = (const float*)d_in[2];
    const float* invK  = (const float*)d_in[3];
    const float* pose  = (const float*)d_in[4];
    const int*   seg   = (const int*)d_in[5];
    float* out  = (float*)d_out;
    float* mins = (float*)d_ws;                       // memset 0x7F -> +3.39e38
    float* maxs = (float*)((char*)d_ws + 16);         // memset 0xFF -> -NaN (ok for int-atomics)
    unsigned long long* A = (unsigned long long*)((char*)d_ws + 256);

    hipMemsetAsync(mins, 0x7F, 16, stream);
    hipMemsetAsync(maxs, 0xFF, 16, stream);
    hipMemsetAsync(A, 0, (size_t)BHW * 8, stream);

    int gMain = (BHW + TPB - 1) / TPB;   // 5760 blocks
    k_pass1<<<gMain, TPB, 0, stream>>>(flow, depth, seg, Km, invK, pose, mins, maxs, A);
    k_pass2<<<gMain, TPB, 0, stream>>>(flow, depth, Km, invK, pose, mins, maxs);
    k_pass3<<<gMain, TPB, 0, stream>>>(flow, depth, Km, invK, pose, mins, maxs, A, out);
}

// Round 3
// 350.998 us; speedup vs baseline: 1.5007x; 1.4464x over previous
//
#include <hip/hip_runtime.h>
#include <math.h>

// Match numpy (no FMA contraction) — mask boundary is bit-sensitive.
#pragma clang fp contract(off)

namespace {

constexpr int B = 12, H = 192, W = 640;
constexpr int HW  = H * W;        // 122880
constexpr int BHW = B * HW;       // 1474560
constexpr float EPS = 1e-7f;
constexpr int TPB = 256;

constexpr int TR    = 12;         // target-tile rows per workgroup
constexpr int TILES = H / TR;     // 16 tiles/batch -> 192 wgs

// ws layout: mins[4] floats at +0, maxs[4] floats at +16
//   mins = {fmin, smin, cmin}, maxs = {fmax, smax, cmax}

__device__ __forceinline__ void atomicMinF(float* a, float v) {
    if (v >= 0.0f) atomicMin((int*)a, __float_as_int(v));
    else           atomicMax((unsigned int*)a, __float_as_uint(v));
}
__device__ __forceinline__ void atomicMaxF(float* a, float v) {
    if (v >= 0.0f) atomicMax((int*)a, __float_as_int(v));
    else           atomicMin((unsigned int*)a, __float_as_uint(v));
}

// static flow = project(K@pose, depth*unproject(invK,[x,y,1])) - [x,y]
// Accumulation order mirrors the reference einsums (left-assoc, f32).
__device__ __forceinline__ void static_flow(
    const float* __restrict__ Km, const float* __restrict__ invK,
    const float* __restrict__ pose, int b, int x, int y, float d,
    float& sx, float& sy)
{
    const float* Kb = Km   + b * 16;
    const float* iK = invK + b * 16;
    const float* Po = pose + b * 16;
    float fx = (float)x, fy = (float)y;
    float cam0 = iK[0]*fx + iK[1]*fy + iK[2];
    float cam1 = iK[4]*fx + iK[5]*fy + iK[6];
    float cam2 = iK[8]*fx + iK[9]*fy + iK[10];
    cam0 = d * cam0; cam1 = d * cam1; cam2 = d * cam2;
    float P[12];
#pragma unroll
    for (int i = 0; i < 3; ++i) {
#pragma unroll
        for (int j = 0; j < 4; ++j) {
            float s = Kb[i*4+0] * Po[0*4+j];
            s = s + Kb[i*4+1] * Po[1*4+j];
            s = s + Kb[i*4+2] * Po[2*4+j];
            s = s + Kb[i*4+3] * Po[3*4+j];
            P[i*4+j] = s;
        }
    }
    float cp0 = P[0]*cam0 + P[1]*cam1 + P[2]*cam2  + P[3];
    float cp1 = P[4]*cam0 + P[5]*cam1 + P[6]*cam2  + P[7];
    float cp2 = P[8]*cam0 + P[9]*cam1 + P[10]*cam2 + P[11];
    float pz = cp2 + EPS;
    sx = cp0 / pz - fx;
    sy = cp1 / pz - fy;
}

__device__ __forceinline__ float norm01(float v, float mn, float mx) {
    return (2.0f * (v - mn)) / (mx - mn) - 1.0f;
}

__global__ void k_init(float* __restrict__ mins, float* __restrict__ maxs) {
    int i = threadIdx.x;
    if (i < 4) { mins[i] = INFINITY; maxs[i] = -INFINITY; }
}

// Winner resolution + scatter outputs, NO global atomics.
// One wg per (batch, 12-row target tile). Scan all batch sources with
// coalesced float4 loads; LDS atomicMax(n+1) picks last-write-wins winner;
// writeout gathers exact payload (full-precision -flow, seg) per target.
__global__ void __launch_bounds__(TPB)
k_winner(const float* __restrict__ flow, const int* __restrict__ seg,
         float* __restrict__ out) {
    __shared__ unsigned int win[TR * W];   // 30720 B
    int wg = blockIdx.x;
    int b  = wg / TILES;
    int t0 = (wg - b * TILES) * TR;        // first target row of tile
    for (int i = threadIdx.x; i < TR * W; i += TPB) win[i] = 0u;
    __syncthreads();

    const float* fx_p = flow + b * 2 * HW;
    const float* fy_p = fx_p + HW;

    // HW = 122880 = 120 * (TPB*4), no tail
    for (int s0 = threadIdx.x * 4; s0 < HW; s0 += TPB * 4) {
        float4 fx4 = *(const float4*)(fx_p + s0);
        float4 fy4 = *(const float4*)(fy_p + s0);
        int y = s0 / W;
        int x = s0 - y * W;
        float fxa[4] = {fx4.x, fx4.y, fx4.z, fx4.w};
        float fya[4] = {fy4.x, fy4.y, fy4.z, fy4.w};
#pragma unroll
        for (int j = 0; j < 4; ++j) {
            int xj = x + j, yj = y;
            if (xj >= W) { xj -= W; yj += 1; }
            int cxi = (int)rintf((float)xj + fxa[j]);
            int cyi = (int)rintf((float)yj + fya[j]);
            cxi = min(max(cxi, 0), W - 1);
            cyi = min(max(cyi, 0), H - 1);
            if (cyi >= t0 && cyi < t0 + TR) {
                unsigned key = (unsigned)(s0 + j + 1);   // max key == max n
                atomicMax(&win[(cyi - t0) * W + cxi], key);
            }
        }
    }
    __syncthreads();

    const int* seg_p = seg + b * HW;
    int base = t0 * W;
    for (int t = threadIdx.x; t < TR * W; t += TPB) {
        unsigned k = win[t];
        float bx = 0.0f, by = 0.0f, sg = 0.0f;
        if (k) {
            int n = (int)k - 1;
            bx = -fx_p[n];                 // exact payload via gather
            by = -fy_p[n];
            sg = seg_p[n] ? 1.0f : 0.0f;
        }
        out[BHW + b*2*HW + base + t]      = bx;
        out[BHW + b*2*HW + HW + base + t] = by;
        out[3*BHW + b*HW + base + t]      = sg;
    }
}

// Pass 1: flow & static-flow global min/max (grid-stride, 6 atomics/block)
__global__ void k_red1(const float* __restrict__ flow, const float* __restrict__ depth,
                       const float* __restrict__ Km, const float* __restrict__ invK,
                       const float* __restrict__ pose,
                       float* __restrict__ mins, float* __restrict__ maxs) {
    float fmn = INFINITY, fmx = -INFINITY, smn = INFINITY, smx = -INFINITY;
    int stride = gridDim.x * blockDim.x;
    for (int p = blockIdx.x * blockDim.x + threadIdx.x; p < BHW; p += stride) {
        int b = p / HW;
        int n = p - b * HW;
        int y = n / W;
        int x = n - y * W;
        float fxv = flow[b*2*HW + n];
        float fyv = flow[b*2*HW + HW + n];
        float d   = depth[p];
        float sx, sy;
        static_flow(Km, invK, pose, b, x, y, d, sx, sy);
        fmn = fminf(fmn, fminf(fxv, fyv)); fmx = fmaxf(fmx, fmaxf(fxv, fyv));
        smn = fminf(smn, fminf(sx, sy));   smx = fmaxf(smx, fmaxf(sx, sy));
    }
    for (int off = 32; off; off >>= 1) {
        fmn = fminf(fmn, __shfl_down(fmn, off, 64));
        fmx = fmaxf(fmx, __shfl_down(fmx, off, 64));
        smn = fminf(smn, __shfl_down(smn, off, 64));
        smx = fmaxf(smx, __shfl_down(smx, off, 64));
    }
    __shared__ float s[4][4];
    int lane = threadIdx.x & 63, wv = threadIdx.x >> 6;
    if (lane == 0) { s[wv][0]=fmn; s[wv][1]=fmx; s[wv][2]=smn; s[wv][3]=smx; }
    __syncthreads();
    if (threadIdx.x == 0) {
        float a = s[0][0], bq = s[0][1], c = s[0][2], dq = s[0][3];
#pragma unroll
        for (int w2 = 1; w2 < 4; ++w2) {
            a  = fminf(a,  s[w2][0]); bq = fmaxf(bq, s[w2][1]);
            c  = fminf(c,  s[w2][2]); dq = fmaxf(dq, s[w2][3]);
        }
        atomicMinF(&mins[0], a);  atomicMaxF(&maxs[0], bq);
        atomicMinF(&mins[1], c);  atomicMaxF(&maxs[1], dq);
    }
}

// Pass 2: check min/max (grid-stride)
__global__ void k_red2(const float* __restrict__ flow, const float* __restrict__ depth,
                       const float* __restrict__ Km, const float* __restrict__ invK,
                       const float* __restrict__ pose,
                       float* __restrict__ mins, float* __restrict__ maxs) {
    float fmn = mins[0], fmx = maxs[0], smn = mins[1], smx = maxs[1];
    float cmn = INFINITY, cmx = -INFINITY;
    int stride = gridDim.x * blockDim.x;
    for (int p = blockIdx.x * blockDim.x + threadIdx.x; p < BHW; p += stride) {
        int b = p / HW;
        int n = p - b * HW;
        int y = n / W;
        int x = n - y * W;
        float fxv = flow[b*2*HW + n];
        float fyv = flow[b*2*HW + HW + n];
        float d   = depth[p];
        float sx, sy;
        static_flow(Km, invK, pose, b, x, y, d, sx, sy);
        float dx = norm01(fxv, fmn, fmx) - norm01(sx, smn, smx);
        float dy = norm01(fyv, fmn, fmx) - norm01(sy, smn, smx);
        float c = sqrtf(dx*dx + dy*dy);
        cmn = fminf(cmn, c); cmx = fmaxf(cmx, c);
    }
    for (int off = 32; off; off >>= 1) {
        cmn = fminf(cmn, __shfl_down(cmn, off, 64));
        cmx = fmaxf(cmx, __shfl_down(cmx, off, 64));
    }
    __shared__ float s[4][2];
    int lane = threadIdx.x & 63, wv = threadIdx.x >> 6;
    if (lane == 0) { s[wv][0] = cmn; s[wv][1] = cmx; }
    __syncthreads();
    if (threadIdx.x == 0) {
        float a = s[0][0], bq = s[0][1];
#pragma unroll
        for (int w2 = 1; w2 < 4; ++w2) { a = fminf(a, s[w2][0]); bq = fmaxf(bq, s[w2][1]); }
        atomicMinF(&mins[2], a);  atomicMaxF(&maxs[2], bq);
    }
}

// Pass 3: mask write only
__global__ void k_mask(const float* __restrict__ flow, const float* __restrict__ depth,
                       const float* __restrict__ Km, const float* __restrict__ invK,
                       const float* __restrict__ pose,
                       const float* __restrict__ mins, const float* __restrict__ maxs,
                       float* __restrict__ out) {
    int p = blockIdx.x * blockDim.x + threadIdx.x;
    if (p >= BHW) return;
    float fmn = mins[0], fmx = maxs[0], smn = mins[1], smx = maxs[1];
    float cmn = mins[2], cmx = maxs[2];
    int b = p / HW;
    int n = p - b * HW;
    int y = n / W;
    int x = n - y * W;
    float fxv = flow[b*2*HW + n];
    float fyv = flow[b*2*HW + HW + n];
    float d   = depth[p];
    float sx, sy;
    static_flow(Km, invK, pose, b, x, y, d, sx, sy);
    float dx = norm01(fxv, fmn, fmx) - norm01(sx, smn, smx);
    float dy = norm01(fyv, fmn, fmx) - norm01(sy, smn, smx);
    float c = sqrtf(dx*dx + dy*dy);
    float cn = (c - cmn) / (cmx - cmn);
    out[p] = (cn < 0.98f) ? 1.0f : 0.0f;
}

} // namespace

extern "C" void kernel_launch(void* const* d_in, const int* in_sizes, int n_in,
                              void* d_out, int out_size, void* d_ws, size_t ws_size,
                              hipStream_t stream) {
    const float* flow  = (const float*)d_in[0];
    const float* depth = (const float*)d_in[1];
    const float* Km    = (const float*)d_in[2];
    const float* invK  = (const float*)d_in[3];
    const float* pose  = (const float*)d_in[4];
    const int*   seg   = (const int*)d_in[5];
    float* out  = (float*)d_out;
    float* mins = (float*)d_ws;
    float* maxs = (float*)((char*)d_ws + 16);

    int gRed  = 2048;                    // grid-stride reductions
    int gMask = (BHW + TPB - 1) / TPB;   // 5760 blocks
    k_init  <<<1, 64, 0, stream>>>(mins, maxs);
    k_winner<<<B * TILES, TPB, 0, stream>>>(flow, seg, out);
    k_red1  <<<gRed, TPB, 0, stream>>>(flow, depth, Km, invK, pose, mins, maxs);
    k_red2  <<<gRed, TPB, 0, stream>>>(flow, depth, Km, invK, pose, mins, maxs);
    k_mask  <<<gMask, TPB, 0, stream>>>(flow, depth, Km, invK, pose, mins, maxs, out);
}

// Round 4
// 276.813 us; speedup vs baseline: 1.9028x; 1.2680x over previous
//
#include <hip/hip_runtime.h>
#include <math.h>

// Match numpy (no FMA contraction) — mask boundary is bit-sensitive.
#pragma clang fp contract(off)

namespace {

constexpr int B = 12, H = 192, W = 640;
constexpr int HW  = H * W;        // 122880
constexpr int BHW = B * HW;       // 1474560
constexpr float EPS = 1e-7f;
constexpr int TPB = 256;

constexpr int TR    = 12;         // target-tile rows per workgroup
constexpr int TILES = H / TR;     // 16 tiles/batch
constexpr int TRW   = TR * W;     // 7680 targets per tile
constexpr int SC    = 2;          // source chunks per tile
constexpr int HWC   = HW / SC;    // 61440 sources per chunk
constexpr int WTPB  = 1024;       // k_winner block size

// ws layout: mins[4] @ +0, maxs[4] @ +16, partial winners u32 @ +256
//   partial[((b*TILES + tile)*SC + chunk)*TRW + off]  — 11.8 MB total

__device__ __forceinline__ void atomicMinF(float* a, float v) {
    if (v >= 0.0f) atomicMin((int*)a, __float_as_int(v));
    else           atomicMax((unsigned int*)a, __float_as_uint(v));
}
__device__ __forceinline__ void atomicMaxF(float* a, float v) {
    if (v >= 0.0f) atomicMax((int*)a, __float_as_int(v));
    else           atomicMin((unsigned int*)a, __float_as_uint(v));
}

// static flow = project(K@pose, depth*unproject(invK,[x,y,1])) - [x,y]
// Accumulation order mirrors the reference einsums (left-assoc, f32).
__device__ __forceinline__ void static_flow(
    const float* __restrict__ Km, const float* __restrict__ invK,
    const float* __restrict__ pose, int b, int x, int y, float d,
    float& sx, float& sy)
{
    const float* Kb = Km   + b * 16;
    const float* iK = invK + b * 16;
    const float* Po = pose + b * 16;
    float fx = (float)x, fy = (float)y;
    float cam0 = iK[0]*fx + iK[1]*fy + iK[2];
    float cam1 = iK[4]*fx + iK[5]*fy + iK[6];
    float cam2 = iK[8]*fx + iK[9]*fy + iK[10];
    cam0 = d * cam0; cam1 = d * cam1; cam2 = d * cam2;
    float P[12];
#pragma unroll
    for (int i = 0; i < 3; ++i) {
#pragma unroll
        for (int j = 0; j < 4; ++j) {
            float s = Kb[i*4+0] * Po[0*4+j];
            s = s + Kb[i*4+1] * Po[1*4+j];
            s = s + Kb[i*4+2] * Po[2*4+j];
            s = s + Kb[i*4+3] * Po[3*4+j];
            P[i*4+j] = s;
        }
    }
    float cp0 = P[0]*cam0 + P[1]*cam1 + P[2]*cam2  + P[3];
    float cp1 = P[4]*cam0 + P[5]*cam1 + P[6]*cam2  + P[7];
    float cp2 = P[8]*cam0 + P[9]*cam1 + P[10]*cam2 + P[11];
    float pz = cp2 + EPS;
    sx = cp0 / pz - fx;
    sy = cp1 / pz - fy;
}

__device__ __forceinline__ float norm01(float v, float mn, float mx) {
    return (2.0f * (v - mn)) / (mx - mn) - 1.0f;
}

__global__ void k_init(float* __restrict__ mins, float* __restrict__ maxs) {
    int i = threadIdx.x;
    if (i < 4) { mins[i] = INFINITY; maxs[i] = -INFINITY; }
}

// Stage 1: per-(batch, target-tile, source-chunk) winner resolution in LDS,
// partial winner array written coalesced to ws. No global atomics.
__global__ void __launch_bounds__(WTPB)
k_winner(const float* __restrict__ flow, unsigned int* __restrict__ partial) {
    __shared__ unsigned int win[TRW];   // 30720 B
    int wg    = blockIdx.x;             // ((b*TILES + tile)*SC + chunk)
    int chunk = wg % SC;
    int bt    = wg / SC;
    int b     = bt / TILES;
    int t0    = (bt - b * TILES) * TR;  // first target row of tile
    for (int i = threadIdx.x; i < TRW; i += WTPB) win[i] = 0u;
    __syncthreads();

    const float* fx_p = flow + b * 2 * HW;
    const float* fy_p = fx_p + HW;

    // HWC = 61440 = 15 * (WTPB*4), no tail
    int s_end = (chunk + 1) * HWC;
    for (int s0 = chunk * HWC + threadIdx.x * 4; s0 < s_end; s0 += WTPB * 4) {
        float4 fx4 = *(const float4*)(fx_p + s0);
        float4 fy4 = *(const float4*)(fy_p + s0);
        int y = s0 / W;
        int x = s0 - y * W;
        float fxa[4] = {fx4.x, fx4.y, fx4.z, fx4.w};
        float fya[4] = {fy4.x, fy4.y, fy4.z, fy4.w};
#pragma unroll
        for (int j = 0; j < 4; ++j) {
            int xj = x + j, yj = y;
            if (xj >= W) { xj -= W; yj += 1; }
            int cxi = (int)rintf((float)xj + fxa[j]);
            int cyi = (int)rintf((float)yj + fya[j]);
            cxi = min(max(cxi, 0), W - 1);
            cyi = min(max(cyi, 0), H - 1);
            if (cyi >= t0 && cyi < t0 + TR) {
                unsigned key = (unsigned)(s0 + j + 1);   // max key == max n
                atomicMax(&win[(cyi - t0) * W + cxi], key);
            }
        }
    }
    __syncthreads();

    unsigned int* dst = partial + (size_t)wg * TRW;
    for (int t = threadIdx.x; t < TRW; t += WTPB) dst[t] = win[t];
}

// Pass 1: flow & static-flow global min/max (grid-stride, 4 atomics/block)
__global__ void k_red1(const float* __restrict__ flow, const float* __restrict__ depth,
                       const float* __restrict__ Km, const float* __restrict__ invK,
                       const float* __restrict__ pose,
                       float* __restrict__ mins, float* __restrict__ maxs) {
    float fmn = INFINITY, fmx = -INFINITY, smn = INFINITY, smx = -INFINITY;
    int stride = gridDim.x * blockDim.x;
    for (int p = blockIdx.x * blockDim.x + threadIdx.x; p < BHW; p += stride) {
        int b = p / HW;
        int n = p - b * HW;
        int y = n / W;
        int x = n - y * W;
        float fxv = flow[b*2*HW + n];
        float fyv = flow[b*2*HW + HW + n];
        float d   = depth[p];
        float sx, sy;
        static_flow(Km, invK, pose, b, x, y, d, sx, sy);
        fmn = fminf(fmn, fminf(fxv, fyv)); fmx = fmaxf(fmx, fmaxf(fxv, fyv));
        smn = fminf(smn, fminf(sx, sy));   smx = fmaxf(smx, fmaxf(sx, sy));
    }
    for (int off = 32; off; off >>= 1) {
        fmn = fminf(fmn, __shfl_down(fmn, off, 64));
        fmx = fmaxf(fmx, __shfl_down(fmx, off, 64));
        smn = fminf(smn, __shfl_down(smn, off, 64));
        smx = fmaxf(smx, __shfl_down(smx, off, 64));
    }
    __shared__ float s[4][4];
    int lane = threadIdx.x & 63, wv = threadIdx.x >> 6;
    if (lane == 0) { s[wv][0]=fmn; s[wv][1]=fmx; s[wv][2]=smn; s[wv][3]=smx; }
    __syncthreads();
    if (threadIdx.x == 0) {
        float a = s[0][0], bq = s[0][1], c = s[0][2], dq = s[0][3];
#pragma unroll
        for (int w2 = 1; w2 < 4; ++w2) {
            a  = fminf(a,  s[w2][0]); bq = fmaxf(bq, s[w2][1]);
            c  = fminf(c,  s[w2][2]); dq = fmaxf(dq, s[w2][3]);
        }
        atomicMinF(&mins[0], a);  atomicMaxF(&maxs[0], bq);
        atomicMinF(&mins[1], c);  atomicMaxF(&maxs[1], dq);
    }
}

// Pass 2: check min/max (grid-stride)
__global__ void k_red2(const float* __restrict__ flow, const float* __restrict__ depth,
                       const float* __restrict__ Km, const float* __restrict__ invK,
                       const float* __restrict__ pose,
                       float* __restrict__ mins, float* __restrict__ maxs) {
    float fmn = mins[0], fmx = maxs[0], smn = mins[1], smx = maxs[1];
    float cmn = INFINITY, cmx = -INFINITY;
    int stride = gridDim.x * blockDim.x;
    for (int p = blockIdx.x * blockDim.x + threadIdx.x; p < BHW; p += stride) {
        int b = p / HW;
        int n = p - b * HW;
        int y = n / W;
        int x = n - y * W;
        float fxv = flow[b*2*HW + n];
        float fyv = flow[b*2*HW + HW + n];
        float d   = depth[p];
        float sx, sy;
        static_flow(Km, invK, pose, b, x, y, d, sx, sy);
        float dx = norm01(fxv, fmn, fmx) - norm01(sx, smn, smx);
        float dy = norm01(fyv, fmn, fmx) - norm01(sy, smn, smx);
        float c = sqrtf(dx*dx + dy*dy);
        cmn = fminf(cmn, c); cmx = fmaxf(cmx, c);
    }
    for (int off = 32; off; off >>= 1) {
        cmn = fminf(cmn, __shfl_down(cmn, off, 64));
        cmx = fmaxf(cmx, __shfl_down(cmx, off, 64));
    }
    __shared__ float s[4][2];
    int lane = threadIdx.x & 63, wv = threadIdx.x >> 6;
    if (lane == 0) { s[wv][0] = cmn; s[wv][1] = cmx; }
    __syncthreads();
    if (threadIdx.x == 0) {
        float a = s[0][0], bq = s[0][1];
#pragma unroll
        for (int w2 = 1; w2 < 4; ++w2) { a = fminf(a, s[w2][0]); bq = fmaxf(bq, s[w2][1]); }
        atomicMinF(&mins[2], a);  atomicMaxF(&maxs[2], bq);
    }
}

// Pass 3: mask write + fused partial-winner merge + exact-payload scatter out.
__global__ void k_mask(const float* __restrict__ flow, const float* __restrict__ depth,
                       const int* __restrict__ seg,
                       const float* __restrict__ Km, const float* __restrict__ invK,
                       const float* __restrict__ pose,
                       const float* __restrict__ mins, const float* __restrict__ maxs,
                       const unsigned int* __restrict__ partial,
                       float* __restrict__ out) {
    int p = blockIdx.x * blockDim.x + threadIdx.x;
    if (p >= BHW) return;
    float fmn = mins[0], fmx = maxs[0], smn = mins[1], smx = maxs[1];
    float cmn = mins[2], cmx = maxs[2];
    int b = p / HW;
    int n = p - b * HW;
    int y = n / W;
    int x = n - y * W;
    float fxv = flow[b*2*HW + n];
    float fyv = flow[b*2*HW + HW + n];
    float d   = depth[p];
    float sx, sy;
    static_flow(Km, invK, pose, b, x, y, d, sx, sy);
    float dx = norm01(fxv, fmn, fmx) - norm01(sx, smn, smx);
    float dy = norm01(fyv, fmn, fmx) - norm01(sy, smn, smx);
    float c = sqrtf(dx*dx + dy*dy);
    float cn = (c - cmn) / (cmx - cmn);
    out[p] = (cn < 0.98f) ? 1.0f : 0.0f;

    // merge SC partial winners for target (b, n) — coalesced reads
    int tile = y / TR;
    int off  = n - tile * TRW;
    const unsigned int* base = partial + ((size_t)(b * TILES + tile) * SC) * TRW + off;
    unsigned k = base[0];
#pragma unroll
    for (int cch = 1; cch < SC; ++cch) k = max(k, base[(size_t)cch * TRW]);

    float bx = 0.0f, by = 0.0f, sg = 0.0f;
    if (k) {
        int nw = (int)k - 1;                       // winning source index
        bx = -flow[b*2*HW + nw];                   // exact payload via gather
        by = -flow[b*2*HW + HW + nw];
        sg = seg[b*HW + nw] ? 1.0f : 0.0f;
    }
    out[BHW + b*2*HW + n]      = bx;
    out[BHW + b*2*HW + HW + n] = by;
    out[3*BHW + p]             = sg;
}

} // namespace

extern "C" void kernel_launch(void* const* d_in, const int* in_sizes, int n_in,
                              void* d_out, int out_size, void* d_ws, size_t ws_size,
                              hipStream_t stream) {
    const float* flow  = (const float*)d_in[0];
    const float* depth = (const float*)d_in[1];
    const float* Km    = (const float*)d_in[2];
    const float* invK  = (const float*)d_in[3];
    const float* pose  = (const float*)d_in[4];
    const int*   seg   = (const int*)d_in[5];
    float* out  = (float*)d_out;
    float* mins = (float*)d_ws;
    float* maxs = (float*)((char*)d_ws + 16);
    unsigned int* partial = (unsigned int*)((char*)d_ws + 256);  // 11.8 MB

    int gRed  = 2048;                    // grid-stride reductions
    int gMask = (BHW + TPB - 1) / TPB;   // 5760 blocks
    k_init  <<<1, 64, 0, stream>>>(mins, maxs);
    k_winner<<<B * TILES * SC, WTPB, 0, stream>>>(flow, partial);
    k_red1  <<<gRed, TPB, 0, stream>>>(flow, depth, Km, invK, pose, mins, maxs);
    k_red2  <<<gRed, TPB, 0, stream>>>(flow, depth, Km, invK, pose, mins, maxs);
    k_mask  <<<gMask, TPB, 0, stream>>>(flow, depth, seg, Km, invK, pose,
                                        mins, maxs, partial, out);
}

// Round 5
// 154.237 us; speedup vs baseline: 3.4151x; 1.7947x over previous
//
#include <hip/hip_runtime.h>
#include <math.h>

// Match numpy (no FMA contraction) — mask boundary is bit-sensitive.
#pragma clang fp contract(off)

namespace {

constexpr int B = 12, H = 192, W = 640;
constexpr int HW  = H * W;        // 122880
constexpr int BHW = B * HW;       // 1474560
constexpr float EPS = 1e-7f;
constexpr int TPB = 256;

constexpr int TR    = 12;         // target-tile rows per workgroup
constexpr int TILES = H / TR;     // 16 tiles/batch
constexpr int TRW   = TR * W;     // 7680 targets per tile
constexpr int SC    = 2;          // source chunks per tile
constexpr int HWC   = HW / SC;    // 61440 sources per chunk
constexpr int WTPB  = 1024;       // k_winner block size

constexpr int RTPB  = 1024;       // reduction block size
constexpr int RBLK  = 256;        // reduction grid: 1 block/CU; ONLY 4 (2)
                                  // same-line atomics per block — the
                                  // contended-RMW tail is ~12.5 ns each.

// ws layout: mins[4] @ +0, maxs[4] @ +16, partial winners u32 @ +256
//   partial[((b*TILES + tile)*SC + chunk)*TRW + off]  — 11.8 MB total

__device__ __forceinline__ void atomicMinF(float* a, float v) {
    if (v >= 0.0f) atomicMin((int*)a, __float_as_int(v));
    else           atomicMax((unsigned int*)a, __float_as_uint(v));
}
__device__ __forceinline__ void atomicMaxF(float* a, float v) {
    if (v >= 0.0f) atomicMax((int*)a, __float_as_int(v));
    else           atomicMin((unsigned int*)a, __float_as_uint(v));
}

// static flow = project(K@pose, depth*unproject(invK,[x,y,1])) - [x,y]
// Accumulation order mirrors the reference einsums (left-assoc, f32).
__device__ __forceinline__ void static_flow(
    const float* __restrict__ Km, const float* __restrict__ invK,
    const float* __restrict__ pose, int b, int x, int y, float d,
    float& sx, float& sy)
{
    const float* Kb = Km   + b * 16;
    const float* iK = invK + b * 16;
    const float* Po = pose + b * 16;
    float fx = (float)x, fy = (float)y;
    float cam0 = iK[0]*fx + iK[1]*fy + iK[2];
    float cam1 = iK[4]*fx + iK[5]*fy + iK[6];
    float cam2 = iK[8]*fx + iK[9]*fy + iK[10];
    cam0 = d * cam0; cam1 = d * cam1; cam2 = d * cam2;
    float P[12];
#pragma unroll
    for (int i = 0; i < 3; ++i) {
#pragma unroll
        for (int j = 0; j < 4; ++j) {
            float s = Kb[i*4+0] * Po[0*4+j];
            s = s + Kb[i*4+1] * Po[1*4+j];
            s = s + Kb[i*4+2] * Po[2*4+j];
            s = s + Kb[i*4+3] * Po[3*4+j];
            P[i*4+j] = s;
        }
    }
    float cp0 = P[0]*cam0 + P[1]*cam1 + P[2]*cam2  + P[3];
    float cp1 = P[4]*cam0 + P[5]*cam1 + P[6]*cam2  + P[7];
    float cp2 = P[8]*cam0 + P[9]*cam1 + P[10]*cam2 + P[11];
    float pz = cp2 + EPS;
    sx = cp0 / pz - fx;
    sy = cp1 / pz - fy;
}

__device__ __forceinline__ float norm01(float v, float mn, float mx) {
    return (2.0f * (v - mn)) / (mx - mn) - 1.0f;
}

// Stage 1: per-(batch, target-tile, source-chunk) winner resolution in LDS,
// partial winner array written coalesced to ws. No global atomics.
// Block 0 also initializes mins/maxs (no reader until the next dispatch).
__global__ void __launch_bounds__(WTPB)
k_winner(const float* __restrict__ flow, unsigned int* __restrict__ partial,
         float* __restrict__ mins, float* __restrict__ maxs) {
    if (blockIdx.x == 0 && threadIdx.x < 4) {
        mins[threadIdx.x] = INFINITY;
        maxs[threadIdx.x] = -INFINITY;
    }
    __shared__ unsigned int win[TRW];   // 30720 B
    int wg    = blockIdx.x;             // ((b*TILES + tile)*SC + chunk)
    int chunk = wg % SC;
    int bt    = wg / SC;
    int b     = bt / TILES;
    int t0    = (bt - b * TILES) * TR;  // first target row of tile
    for (int i = threadIdx.x; i < TRW; i += WTPB) win[i] = 0u;
    __syncthreads();

    const float* fx_p = flow + b * 2 * HW;
    const float* fy_p = fx_p + HW;

    // HWC = 61440 = 15 * (WTPB*4), no tail
    int s_end = (chunk + 1) * HWC;
    for (int s0 = chunk * HWC + threadIdx.x * 4; s0 < s_end; s0 += WTPB * 4) {
        float4 fx4 = *(const float4*)(fx_p + s0);
        float4 fy4 = *(const float4*)(fy_p + s0);
        int y = s0 / W;
        int x = s0 - y * W;
        float fxa[4] = {fx4.x, fx4.y, fx4.z, fx4.w};
        float fya[4] = {fy4.x, fy4.y, fy4.z, fy4.w};
#pragma unroll
        for (int j = 0; j < 4; ++j) {
            int xj = x + j, yj = y;
            if (xj >= W) { xj -= W; yj += 1; }
            int cxi = (int)rintf((float)xj + fxa[j]);
            int cyi = (int)rintf((float)yj + fya[j]);
            cxi = min(max(cxi, 0), W - 1);
            cyi = min(max(cyi, 0), H - 1);
            if (cyi >= t0 && cyi < t0 + TR) {
                unsigned key = (unsigned)(s0 + j + 1);   // max key == max n
                atomicMax(&win[(cyi - t0) * W + cxi], key);
            }
        }
    }
    __syncthreads();

    unsigned int* dst = partial + (size_t)wg * TRW;
    for (int t = threadIdx.x; t < TRW; t += WTPB) dst[t] = win[t];
}

// Pass 1: flow & static-flow global min/max. float4 grid-stride (W%4==0 so a
// group never crosses a row/batch boundary); 4 same-line atomics per block.
__global__ void __launch_bounds__(RTPB)
k_red1(const float* __restrict__ flow, const float* __restrict__ depth,
       const float* __restrict__ Km, const float* __restrict__ invK,
       const float* __restrict__ pose,
       float* __restrict__ mins, float* __restrict__ maxs) {
    float fmn = INFINITY, fmx = -INFINITY, smn = INFINITY, smx = -INFINITY;
    int stride = gridDim.x * blockDim.x;
    for (int g = blockIdx.x * blockDim.x + threadIdx.x; g < BHW / 4; g += stride) {
        int p0 = g * 4;
        int b  = p0 / HW;
        int n0 = p0 - b * HW;
        int y  = n0 / W;
        int x0 = n0 - y * W;
        float4 fx4 = *(const float4*)(flow + b*2*HW + n0);
        float4 fy4 = *(const float4*)(flow + b*2*HW + HW + n0);
        float4 d4  = *(const float4*)(depth + p0);
        float fxa[4] = {fx4.x, fx4.y, fx4.z, fx4.w};
        float fya[4] = {fy4.x, fy4.y, fy4.z, fy4.w};
        float da[4]  = {d4.x, d4.y, d4.z, d4.w};
#pragma unroll
        for (int j = 0; j < 4; ++j) {
            float sx, sy;
            static_flow(Km, invK, pose, b, x0 + j, y, da[j], sx, sy);
            fmn = fminf(fmn, fminf(fxa[j], fya[j]));
            fmx = fmaxf(fmx, fmaxf(fxa[j], fya[j]));
            smn = fminf(smn, fminf(sx, sy));
            smx = fmaxf(smx, fmaxf(sx, sy));
        }
    }
    for (int off = 32; off; off >>= 1) {
        fmn = fminf(fmn, __shfl_down(fmn, off, 64));
        fmx = fmaxf(fmx, __shfl_down(fmx, off, 64));
        smn = fminf(smn, __shfl_down(smn, off, 64));
        smx = fmaxf(smx, __shfl_down(smx, off, 64));
    }
    __shared__ float s[RTPB / 64][4];
    int lane = threadIdx.x & 63, wv = threadIdx.x >> 6;
    if (lane == 0) { s[wv][0]=fmn; s[wv][1]=fmx; s[wv][2]=smn; s[wv][3]=smx; }
    __syncthreads();
    if (threadIdx.x == 0) {
        float a = s[0][0], bq = s[0][1], c = s[0][2], dq = s[0][3];
#pragma unroll
        for (int w2 = 1; w2 < RTPB / 64; ++w2) {
            a  = fminf(a,  s[w2][0]); bq = fmaxf(bq, s[w2][1]);
            c  = fminf(c,  s[w2][2]); dq = fmaxf(dq, s[w2][3]);
        }
        atomicMinF(&mins[0], a);  atomicMaxF(&maxs[0], bq);
        atomicMinF(&mins[1], c);  atomicMaxF(&maxs[1], dq);
    }
}

// Pass 2: check min/max. Same structure; 2 same-line atomics per block.
__global__ void __launch_bounds__(RTPB)
k_red2(const float* __restrict__ flow, const float* __restrict__ depth,
       const float* __restrict__ Km, const float* __restrict__ invK,
       const float* __restrict__ pose,
       float* __restrict__ mins, float* __restrict__ maxs) {
    float fmn = mins[0], fmx = maxs[0], smn = mins[1], smx = maxs[1];
    float cmn = INFINITY, cmx = -INFINITY;
    int stride = gridDim.x * blockDim.x;
    for (int g = blockIdx.x * blockDim.x + threadIdx.x; g < BHW / 4; g += stride) {
        int p0 = g * 4;
        int b  = p0 / HW;
        int n0 = p0 - b * HW;
        int y  = n0 / W;
        int x0 = n0 - y * W;
        float4 fx4 = *(const float4*)(flow + b*2*HW + n0);
        float4 fy4 = *(const float4*)(flow + b*2*HW + HW + n0);
        float4 d4  = *(const float4*)(depth + p0);
        float fxa[4] = {fx4.x, fx4.y, fx4.z, fx4.w};
        float fya[4] = {fy4.x, fy4.y, fy4.z, fy4.w};
        float da[4]  = {d4.x, d4.y, d4.z, d4.w};
#pragma unroll
        for (int j = 0; j < 4; ++j) {
            float sx, sy;
            static_flow(Km, invK, pose, b, x0 + j, y, da[j], sx, sy);
            float dx = norm01(fxa[j], fmn, fmx) - norm01(sx, smn, smx);
            float dy = norm01(fya[j], fmn, fmx) - norm01(sy, smn, smx);
            float c = sqrtf(dx*dx + dy*dy);
            cmn = fminf(cmn, c); cmx = fmaxf(cmx, c);
        }
    }
    for (int off = 32; off; off >>= 1) {
        cmn = fminf(cmn, __shfl_down(cmn, off, 64));
        cmx = fmaxf(cmx, __shfl_down(cmx, off, 64));
    }
    __shared__ float s[RTPB / 64][2];
    int lane = threadIdx.x & 63, wv = threadIdx.x >> 6;
    if (lane == 0) { s[wv][0] = cmn; s[wv][1] = cmx; }
    __syncthreads();
    if (threadIdx.x == 0) {
        float a = s[0][0], bq = s[0][1];
#pragma unroll
        for (int w2 = 1; w2 < RTPB / 64; ++w2) {
            a = fminf(a, s[w2][0]); bq = fmaxf(bq, s[w2][1]);
        }
        atomicMinF(&mins[2], a);  atomicMaxF(&maxs[2], bq);
    }
}

// Pass 3: mask write + fused partial-winner merge + exact-payload scatter out.
__global__ void k_mask(const float* __restrict__ flow, const float* __restrict__ depth,
                       const int* __restrict__ seg,
                       const float* __restrict__ Km, const float* __restrict__ invK,
                       const float* __restrict__ pose,
                       const float* __restrict__ mins, const float* __restrict__ maxs,
                       const unsigned int* __restrict__ partial,
                       float* __restrict__ out) {
    int p = blockIdx.x * blockDim.x + threadIdx.x;
    if (p >= BHW) return;
    float fmn = mins[0], fmx = maxs[0], smn = mins[1], smx = maxs[1];
    float cmn = mins[2], cmx = maxs[2];
    int b = p / HW;
    int n = p - b * HW;
    int y = n / W;
    int x = n - y * W;
    float fxv = flow[b*2*HW + n];
    float fyv = flow[b*2*HW + HW + n];
    float d   = depth[p];
    float sx, sy;
    static_flow(Km, invK, pose, b, x, y, d, sx, sy);
    float dx = norm01(fxv, fmn, fmx) - norm01(sx, smn, smx);
    float dy = norm01(fyv, fmn, fmx) - norm01(sy, smn, smx);
    float c = sqrtf(dx*dx + dy*dy);
    float cn = (c - cmn) / (cmx - cmn);
    out[p] = (cn < 0.98f) ? 1.0f : 0.0f;

    // merge SC partial winners for target (b, n) — coalesced reads
    int tile = y / TR;
    int off  = n - tile * TRW;
    const unsigned int* base = partial + ((size_t)(b * TILES + tile) * SC) * TRW + off;
    unsigned k = base[0];
#pragma unroll
    for (int cch = 1; cch < SC; ++cch) k = max(k, base[(size_t)cch * TRW]);

    float bx = 0.0f, by = 0.0f, sg = 0.0f;
    if (k) {
        int nw = (int)k - 1;                       // winning source index
        bx = -flow[b*2*HW + nw];                   // exact payload via gather
        by = -flow[b*2*HW + HW + nw];
        sg = seg[b*HW + nw] ? 1.0f : 0.0f;
    }
    out[BHW + b*2*HW + n]      = bx;
    out[BHW + b*2*HW + HW + n] = by;
    out[3*BHW + p]             = sg;
}

} // namespace

extern "C" void kernel_launch(void* const* d_in, const int* in_sizes, int n_in,
                              void* d_out, int out_size, void* d_ws, size_t ws_size,
                              hipStream_t stream) {
    const float* flow  = (const float*)d_in[0];
    const float* depth = (const float*)d_in[1];
    const float* Km    = (const float*)d_in[2];
    const float* invK  = (const float*)d_in[3];
    const float* pose  = (const float*)d_in[4];
    const int*   seg   = (const int*)d_in[5];
    float* out  = (float*)d_out;
    float* mins = (float*)d_ws;
    float* maxs = (float*)((char*)d_ws + 16);
    unsigned int* partial = (unsigned int*)((char*)d_ws + 256);  // 11.8 MB

    int gMask = (BHW + TPB - 1) / TPB;   // 5760 blocks
    k_winner<<<B * TILES * SC, WTPB, 0, stream>>>(flow, partial, mins, maxs);
    k_red1  <<<RBLK, RTPB, 0, stream>>>(flow, depth, Km, invK, pose, mins, maxs);
    k_red2  <<<RBLK, RTPB, 0, stream>>>(flow, depth, Km, invK, pose, mins, maxs);
    k_mask  <<<gMask, TPB, 0, stream>>>(flow, depth, seg, Km, invK, pose,
                                        mins, maxs, partial, out);
}